// Round 20
// baseline (110.654 us; speedup 1.0000x reference)
//
#include <hip/hip_runtime.h>
#include <hip/hip_bf16.h>

typedef __bf16 bf16;
typedef __attribute__((ext_vector_type(8))) __bf16 bf16x8;
typedef __attribute__((ext_vector_type(4))) __bf16 bf16x4;
typedef __attribute__((ext_vector_type(4))) float f32x4;

#define GLOAD_LDS16(g, l) __builtin_amdgcn_global_load_lds( \
    (const __attribute__((address_space(1))) void*)(g),     \
    (__attribute__((address_space(3))) void*)(l), 16, 0, 0)

#if __has_builtin(__builtin_amdgcn_exp2f)
#define EXP2F(x) __builtin_amdgcn_exp2f(x)
#else
#define EXP2F(x) exp2f(x)
#endif

constexpr int MTOT = 4096;   // BS*QLEN
constexpr int DIMC = 1024;
constexpr int QL   = 2048;
constexpr int NH   = 16;
constexpr int HD   = 64;
constexpr float LOG2E = 1.44269504088896340736f;

// ---------------- merged prep: fp32->bf16 for X + 4 weights, and Mexp = exp(mask) ----
__global__ __launch_bounds__(256) void prep_cvt(
    const float* __restrict__ x,  const float* __restrict__ qw,
    const float* __restrict__ kw, const float* __restrict__ vw,
    const float* __restrict__ ow, const float* __restrict__ mask,
    bf16* __restrict__ Xb, bf16* __restrict__ Wq, bf16* __restrict__ Wk,
    bf16* __restrict__ Wv, bf16* __restrict__ Wo, bf16* __restrict__ Mexp)
{
  const long long bid = blockIdx.x;
  if (bid >= 8192) {   // Mexp: 2*2048 fp32 -> bf16 exp(mask)
    const int off = (int)(bid - 8192) * 1024 + threadIdx.x * 4;
    float4 f = *reinterpret_cast<const float4*>(mask + off);
    bf16x4 v;
    v[0] = (bf16)exp2f(f.x * LOG2E); v[1] = (bf16)exp2f(f.y * LOG2E);
    v[2] = (bf16)exp2f(f.z * LOG2E); v[3] = (bf16)exp2f(f.w * LOG2E);
    *reinterpret_cast<bf16x4*>(Mexp + off) = v;
    return;
  }
  const long long i = (bid * 256 + threadIdx.x) * 4;
  const long long nX = (long long)MTOT * DIMC;      // 4M
  const long long nW = (long long)DIMC * DIMC;      // 1M
  const float* src; bf16* dst; long long off;
  if      (i < nX)          { src = x;  dst = Xb; off = i; }
  else if (i < nX + nW)     { src = qw; dst = Wq; off = i - nX; }
  else if (i < nX + 2*nW)   { src = kw; dst = Wk; off = i - nX - nW; }
  else if (i < nX + 3*nW)   { src = vw; dst = Wv; off = i - nX - 2*nW; }
  else                      { src = ow; dst = Wo; off = i - nX - 3*nW; }
  float4 f = *reinterpret_cast<const float4*>(src + off);
  bf16x4 v;
  v[0] = (bf16)f.x; v[1] = (bf16)f.y; v[2] = (bf16)f.z; v[3] = (bf16)f.w;
  *reinterpret_cast<bf16x4*>(dst + off) = v;
}

// ---------------- QKV GEMM (bf16 out): C = (A W^T + bias) * scale ----
// 128 threads = 2 waves; wave w owns cols [w*64, +64), all 128 rows (0.375
// ds_reads/MFMA). Single-buffer 32KB LDS -> 3 blocks/CU resident (grid-limited);
// XCD-aware bijective remap (768 = 8*96): each XCD runs 32-consecutive-x runs
// at fixed (y,z) -> W panel stays hot in that XCD's L2, A-panel sharers cluster.
// Both-sides XOR swizzle (T2). z==2: tile TRANSPOSED to Vt, cols scaled by Mexp.
__global__ __launch_bounds__(128, 2) void gemm_bt(
    const bf16* __restrict__ A,
    const bf16* __restrict__ W0, const bf16* __restrict__ W1, const bf16* __restrict__ W2,
    const float* __restrict__ b0, const float* __restrict__ b1, const float* __restrict__ b2,
    bf16* __restrict__ D0, bf16* __restrict__ D1,
    bf16* __restrict__ VtOut, const bf16* __restrict__ Mexp, float scale0)
{
  __shared__ __align__(16) bf16 SMEM[16384];   // As | Bs, reused as T in z==2 epilogue
  bf16* As = SMEM;          // [128][64]
  bf16* Bs = SMEM + 8192;   // [128][64]

  // XCD-aware remap: flat (HW dispatch order, x fastest) -> logical; 768 = 8*96
  const int flat = blockIdx.x + 32 * (blockIdx.y + 8 * blockIdx.z);
  const int logical = (flat & 7) * 96 + (flat >> 3);
  const int lx  = logical & 31;          // tile row idx 0..31
  const int rem = logical >> 5;          // 0..23
  const int ly  = rem & 7;               // tile col idx 0..7
  const int z   = rem >> 3;              // GEMM selector 0..2

  const bf16* Bm; const float* bias; bf16* D = nullptr; float scale = 1.f;
  if (z == 0)      { Bm = W0; bias = b0; D = D0; scale = scale0; }
  else if (z == 1) { Bm = W1; bias = b1; D = D1; }
  else             { Bm = W2; bias = b2; }

  const int tid  = threadIdx.x;
  const int w    = tid >> 6, lane = tid & 63;
  const int gm0  = lx * 128, gn0 = ly * 128;
  const int wc   = w * 64;
  const int lr   = lane & 15;
  const int lkB  = (lane >> 4) * 16;                 // fragment byte col base
  const int srow = (w << 3) + (lane >> 3);           // staged row within a 16-row pass
  const int scolE = (((lane & 7) * 16) ^ (((lane >> 3) & 7) << 4)) >> 1;  // pre-swz src col

  f32x4 acc[8][4] = {};

  for (int kt = 0; kt < DIMC / 64; ++kt) {
    __syncthreads();
    const int k0 = kt * 64;
#pragma unroll
    for (int p = 0; p < 8; ++p) {
      const int r = p * 16 + srow;
      GLOAD_LDS16(A  + (size_t)(gm0 + r) * DIMC + k0 + scolE, &As[(p * 16 + (w << 3)) * 64]);
      GLOAD_LDS16(Bm + (size_t)(gn0 + r) * DIMC + k0 + scolE, &Bs[(p * 16 + (w << 3)) * 64]);
    }
    asm volatile("s_waitcnt vmcnt(0)" ::: "memory");
    __syncthreads();

#pragma unroll
    for (int kk = 0; kk < 2; ++kk) {
      bf16x8 af[8], bfv[4];
#pragma unroll
      for (int mf = 0; mf < 8; ++mf) {
        const int r = mf * 16 + lr;
        const int cE = ((kk * 64 + lkB) ^ ((r & 7) << 4)) >> 1;
        af[mf] = *reinterpret_cast<const bf16x8*>(&As[r * 64 + cE]);
      }
#pragma unroll
      for (int nf = 0; nf < 4; ++nf) {
        const int r = wc + nf * 16 + lr;
        const int cE = ((kk * 64 + lkB) ^ ((r & 7) << 4)) >> 1;
        bfv[nf] = *reinterpret_cast<const bf16x8*>(&Bs[r * 64 + cE]);
      }
#pragma unroll
      for (int mf = 0; mf < 8; ++mf)
#pragma unroll
        for (int nf = 0; nf < 4; ++nf)
          acc[mf][nf] = __builtin_amdgcn_mfma_f32_16x16x32_bf16(af[mf], bfv[nf], acc[mf][nf], 0, 0, 0);
    }
  }

  const int orow = (lane >> 4) * 4;

  if (z == 2) {
    // ---- transposed epilogue: acc -> T (swizzled LDS, b64 writes) -> Vt ----
    bf16* T = SMEM;                      // [128 c][128 r], r XOR-swizzled by (c&7)<<3
    __syncthreads();                     // all waves done reading As/Bs
#pragma unroll
    for (int mf = 0; mf < 8; ++mf) {
#pragma unroll
      for (int nf = 0; nf < 4; ++nf) {
        const int cl = wc + nf * 16 + lr;
        const float bv = bias[gn0 + cl];
        const int xx = (cl & 7) << 3;
        const int rl0 = mf * 16 + orow;            // 4-aligned; +i contiguous after XOR
        bf16x4 tv;
#pragma unroll
        for (int i = 0; i < 4; ++i) tv[i] = (bf16)(acc[mf][nf][i] + bv);
        *reinterpret_cast<bf16x4*>(&T[cl * 128 + (rl0 ^ xx)]) = tv;
      }
    }
    __syncthreads();
    // thread t: row c = tid (0..127), 16 b128 chunks over the 128 kv, staggered
    const int c   = tid;
    const int xx2 = (c & 7) << 3;
    const int cg  = gn0 + c;                       // global col in [0,1024)
    const int bb  = gm0 >> 11;                     // batch
    const int kvb = gm0 & 2047;                    // kv base within batch
    bf16* vtrow = VtOut + (((size_t)bb * 16 + (cg >> 6)) * 64 + (cg & 63)) * (size_t)QL
                  + kvb;
    const bf16* mrow = Mexp + (size_t)bb * QL + kvb;
    const int st = c & 15;
#pragma unroll
    for (int j = 0; j < 16; ++j) {
      const int jj = (j + st) & 15;
      bf16x8 vv = *reinterpret_cast<const bf16x8*>(&T[c * 128 + ((jj * 8) ^ xx2)]);
      const bf16x8 me = *reinterpret_cast<const bf16x8*>(mrow + jj * 8);
#pragma unroll
      for (int e = 0; e < 8; ++e) vv[e] = (bf16)((float)vv[e] * (float)me[e]);
      *reinterpret_cast<bf16x8*>(vtrow + jj * 8) = vv;
    }
    return;
  }

  // ---- normal epilogue (bf16) ----
#pragma unroll
  for (int mf = 0; mf < 8; ++mf) {
#pragma unroll
    for (int nf = 0; nf < 4; ++nf) {
      const int c = gn0 + wc + nf * 16 + lr;
      const float bv = bias[c];
#pragma unroll
      for (int i = 0; i < 4; ++i) {
        const int r = gm0 + mf * 16 + orow + i;
        D[(size_t)r * DIMC + c] = (bf16)((acc[mf][nf][i] + bv) * scale);
      }
    }
  }
}

// ---------------- Output projection GEMM (fp32 out): 128x64 tiles, swizzled ----
// XCD-aware bijective remap (512 = 8*64): W panel hot per XCD.
__global__ __launch_bounds__(256) void gemm_o(
    const bf16* __restrict__ A, const bf16* __restrict__ W,
    const float* __restrict__ bias, float* __restrict__ out)
{
  __shared__ __align__(16) bf16 As[128 * 64];
  __shared__ __align__(16) bf16 Bs[64 * 64];

  const int flat = blockIdx.x + 32 * blockIdx.y;
  const int logical = (flat & 7) * 64 + (flat >> 3);
  const int lx = logical & 31;
  const int ly = logical >> 5;           // 0..15

  const int tid  = threadIdx.x;
  const int w    = tid >> 6, lane = tid & 63;
  const int gm0  = lx * 128, gn0 = ly * 64;
  const int wr   = (w >> 1) * 64, wc = (w & 1) * 32;
  const int lr   = lane & 15;
  const int lkB  = (lane >> 4) * 16;
  const int srow = (w << 3) + (lane >> 3);
  const int scolE = (((lane & 7) * 16) ^ ((lane >> 3) << 4)) >> 1;

  f32x4 acc[4][2] = {};

  for (int kt = 0; kt < DIMC / 64; ++kt) {
    __syncthreads();
    const int k0 = kt * 64;
#pragma unroll
    for (int p = 0; p < 4; ++p) {
      const int r = p * 32 + srow;
      GLOAD_LDS16(A + (size_t)(gm0 + r) * DIMC + k0 + scolE, &As[(p * 32 + (w << 3)) * 64]);
    }
#pragma unroll
    for (int p = 0; p < 2; ++p) {
      const int r = p * 32 + srow;
      GLOAD_LDS16(W + (size_t)(gn0 + r) * DIMC + k0 + scolE, &Bs[(p * 32 + (w << 3)) * 64]);
    }
    asm volatile("s_waitcnt vmcnt(0)" ::: "memory");
    __syncthreads();

#pragma unroll
    for (int kk = 0; kk < 2; ++kk) {
      bf16x8 af[4], bfv[2];
#pragma unroll
      for (int mf = 0; mf < 4; ++mf) {
        const int r = wr + mf * 16 + lr;
        const int cE = ((kk * 64 + lkB) ^ ((r & 7) << 4)) >> 1;
        af[mf] = *reinterpret_cast<const bf16x8*>(&As[r * 64 + cE]);
      }
#pragma unroll
      for (int nf = 0; nf < 2; ++nf) {
        const int r = wc + nf * 16 + lr;
        const int cE = ((kk * 64 + lkB) ^ ((r & 7) << 4)) >> 1;
        bfv[nf] = *reinterpret_cast<const bf16x8*>(&Bs[r * 64 + cE]);
      }
#pragma unroll
      for (int mf = 0; mf < 4; ++mf)
#pragma unroll
        for (int nf = 0; nf < 2; ++nf)
          acc[mf][nf] = __builtin_amdgcn_mfma_f32_16x16x32_bf16(af[mf], bfv[nf], acc[mf][nf], 0, 0, 0);
    }
  }

  const int orow = (lane >> 4) * 4;
#pragma unroll
  for (int mf = 0; mf < 4; ++mf) {
#pragma unroll
    for (int nf = 0; nf < 2; ++nf) {
      const int c = gn0 + wc + nf * 16 + lr;
      const float bv = bias[c];
#pragma unroll
      for (int i = 0; i < 4; ++i) {
        const int r = gm0 + wr + mf * 16 + orow + i;
        out[(size_t)r * DIMC + c] = acc[mf][nf][i] + bv;
      }
    }
  }
}

// ---------------- Flash attention: 2 q-sets/wave + 2-state cross-tile pipeline ----
// (unchanged — attn is at its LDS-pipe structural plateau ~54 us)
__global__ __launch_bounds__(256, 2) void attn_fwd(
    const bf16* __restrict__ Q, const bf16* __restrict__ K, const bf16* __restrict__ Vt,
    const bf16* __restrict__ Mexp, bf16* __restrict__ ctx)
{
  __shared__ __align__(16) bf16 Kls[4 * 4096];
  __shared__ __align__(16) bf16 Vls[4 * 4096];
  __shared__ __align__(16) bf16 Ps[4][2 * 16 * 36];   // per wave, per q-set [16][36]

  const int tid = threadIdx.x, w = tid >> 6, lane = tid & 63;
  const int bid = blockIdx.x;
  const int logical = (bid & 7) * 64 + (bid >> 3);    // bijective: 512 = 8*64
  const int qt = logical & 15, bh = logical >> 4;     // 4 bh per XCD -> 2MB KV in L2
  const int b = bh >> 4, h = bh & 15;
  const size_t rowbase = (size_t)b * QL;
  const int lr = lane & 15, g = lane >> 4;
  const int lkB = g * 16;   // byte col base of this lane's 16B fragment chunk

  // Q fragments (B operand after swap): 2 sets, rows qt*128 + w*32 + s*16 + lr
  bf16x8 aq[2][2];
#pragma unroll
  for (int s = 0; s < 2; ++s) {
    const bf16* qp = Q + (rowbase + qt * 128 + w * 32 + s * 16 + lr) * DIMC + h * HD + g * 8;
    aq[s][0] = *reinterpret_cast<const bf16x8*>(qp);
    aq[s][1] = *reinterpret_cast<const bf16x8*>(qp + 32);
  }

  // staging geometry: 256 threads, two 16B chunks each per 8KB tile (4 loads total).
  int g_row[2], g_colE[2];
#pragma unroll
  for (int s2 = 0; s2 < 2; ++s2) {
    const int ci = s2 * 256 + tid;
    const int row = ci >> 3;
    g_row[s2]  = row;
    g_colE[s2] = (((ci & 7) * 16) ^ ((row & 7) << 4)) >> 1;
  }
  const bf16* Kt0 = K  + rowbase * DIMC + h * HD;
  const bf16* Vt0 = Vt + (size_t)bh * HD * QL;
  const bf16* MexpP = Mexp + rowbase;

#define ATTN_STAGE(tt, bb) do {                                               \
    _Pragma("unroll")                                                         \
    for (int s2 = 0; s2 < 2; ++s2) {                                          \
      GLOAD_LDS16(Kt0 + (size_t)((tt) * 64 + g_row[s2]) * DIMC + g_colE[s2],  \
                  &Kls[(bb) * 4096 + (s2 * 256 + tid) * 8]);                  \
      GLOAD_LDS16(Vt0 + (size_t)g_row[s2] * QL + (tt) * 64 + g_colE[s2],      \
                  &Vls[(bb) * 4096 + (s2 * 256 + tid) * 8]);                  \
    }                                                                         \
  } while (0)

  const f32x4 zf4 = {0.f, 0.f, 0.f, 0.f};

// QK for both q-sets into state SACC[2][4]; K frags read ONCE, used 2x.
#define QK_COMPUTE(TT, SACC) do {                                             \
    const bf16* Kb = &Kls[((TT) & 3) * 4096];                                 \
    bf16x8 bk0[4], bk1[4];                                                    \
    _Pragma("unroll")                                                         \
    for (int nf = 0; nf < 4; ++nf) {                                          \
      const int r = nf * 16 + lr;                                             \
      const int c0 = ((lkB)      ^ ((r & 7) << 4)) >> 1;                      \
      const int c1 = ((64 + lkB) ^ ((r & 7) << 4)) >> 1;                      \
      bk0[nf] = *reinterpret_cast<const bf16x8*>(&Kb[r * 64 + c0]);           \
      bk1[nf] = *reinterpret_cast<const bf16x8*>(&Kb[r * 64 + c1]);           \
    }                                                                         \
    __builtin_amdgcn_s_setprio(1);                                            \
    _Pragma("unroll")                                                         \
    for (int s = 0; s < 2; ++s)                                               \
      _Pragma("unroll")                                                       \
      for (int nf = 0; nf < 4; ++nf)                                          \
        SACC[s][nf] = __builtin_amdgcn_mfma_f32_16x16x32_bf16(bk0[nf], aq[s][0], zf4, 0, 0, 0); \
    _Pragma("unroll")                                                         \
    for (int s = 0; s < 2; ++s)                                               \
      _Pragma("unroll")                                                       \
      for (int nf = 0; nf < 4; ++nf)                                          \
        SACC[s][nf] = __builtin_amdgcn_mfma_f32_16x16x32_bf16(bk1[nf], aq[s][1], SACC[s][nf], 0, 0, 0); \
    __builtin_amdgcn_s_setprio(0);                                            \
  } while (0)

// softmax + PV for tile TT from state SC, one kk-half.
#define SM_PV_HALF(TT, SC, HALF) do {                                         \
    _Pragma("unroll")                                                         \
    for (int s = 0; s < 2; ++s) {                                             \
      _Pragma("unroll")                                                       \
      for (int nn = 0; nn < 2; ++nn) {                                        \
        const int nf = (HALF) * 2 + nn;                                       \
        const float p0 = EXP2F(SC[s][nf][0]);                                 \
        const float p1 = EXP2F(SC[s][nf][1]);                                 \
        const float p2 = EXP2F(SC[s][nf][2]);                                 \
        const float p3 = EXP2F(SC[s][nf][3]);                                 \
        bf16x4 pv;                                                            \
        pv[0] = (bf16)p0; pv[1] = (bf16)p1; pv[2] = (bf16)p2; pv[3] = (bf16)p3; \
        *reinterpret_cast<bf16x4*>(&Ps[w][s * 576 + lr * 36 + nn * 16 + g * 4]) = pv; \
      }                                                                       \
    }                                                                         \
    const bf16x8 mfrag = *reinterpret_cast<const bf16x8*>(                    \
        MexpP + (TT) * 64 + (HALF) * 32 + g * 8);                             \
    const bf16* Vb = &Vls[((TT) & 3) * 4096];                                 \
    bf16x8 bv[4];                                                             \
    _Pragma("unroll")                                                         \
    for (int df = 0; df < 4; ++df) {                                          \
      const int r = df * 16 + lr;                                             \
      const int cE = (((HALF) * 64 + lkB) ^ ((r & 7) << 4)) >> 1;             \
      bv[df] = *reinterpret_cast<const bf16x8*>(&Vb[r * 64 + cE]);            \
    }                                                                         \
    bf16x8 ap0, ap1;                                                          \
    {                                                                         \
      const bf16x4 lo0 = *reinterpret_cast<const bf16x4*>(&Ps[w][0 * 576 + lr * 36 + g * 8]); \
      const bf16x4 hi0 = *reinterpret_cast<const bf16x4*>(&Ps[w][0 * 576 + lr * 36 + g * 8 + 4]); \
      const bf16x4 lo1 = *reinterpret_cast<const bf16x4*>(&Ps[w][1 * 576 + lr * 36 + g * 8]); \
      const bf16x4 hi1 = *reinterpret_cast<const bf16x4*>(&Ps[w][1 * 576 + lr * 36 + g * 8 + 4]); \
      _Pragma("unroll")                                                       \
      for (int j = 0; j < 4; ++j) {                                           \
        ap0[j] = lo0[j]; ap0[4 + j] = hi0[j];                                 \
        ap1[j] = lo1[j]; ap1[4 + j] = hi1[j];                                 \
      }                                                                       \
    }                                                                         \
    __builtin_amdgcn_s_setprio(1);                                            \
    acc_l[0] = __builtin_amdgcn_mfma_f32_16x16x32_bf16(ap0, mfrag, acc_l[0], 0, 0, 0); \
    acc_l[1] = __builtin_amdgcn_mfma_f32_16x16x32_bf16(ap1, mfrag, acc_l[1], 0, 0, 0); \
    _Pragma("unroll")                                                         \
    for (int df = 0; df < 4; ++df)                                            \
      acc_o[0][df] = __builtin_amdgcn_mfma_f32_16x16x32_bf16(ap0, bv[df], acc_o[0][df], 0, 0, 0); \
    _Pragma("unroll")                                                         \
    for (int df = 0; df < 4; ++df)                                            \
      acc_o[1][df] = __builtin_amdgcn_mfma_f32_16x16x32_bf16(ap1, bv[df], acc_o[1][df], 0, 0, 0); \
    __builtin_amdgcn_s_setprio(0);                                            \
  } while (0)

// counted wait: the newest stage (4 loads) stays in flight; tile T+2 landed.
#define ITER_END() do {                                                       \
    asm volatile("s_waitcnt vmcnt(4) lgkmcnt(0)" ::: "memory");               \
    __builtin_amdgcn_s_barrier();                                             \
    __builtin_amdgcn_sched_barrier(0);                                        \
  } while (0)

  f32x4 acc_l[2] = {};
  f32x4 acc_o[2][4] = {};
  f32x4 sA[2][4], sB[2][4];

  constexpr int NT = QL / 64;   // 32 (even)

  // prologue: stage tiles 0-2 (12 loads); vmcnt(8) -> tile 0 landed; QK(0)->sA;
  // ITER_END vmcnt(4) -> tile 1 landed (tile 2's loads stay in flight).
  ATTN_STAGE(0, 0);
  ATTN_STAGE(1, 1);
  ATTN_STAGE(2, 2);
  asm volatile("s_waitcnt vmcnt(8)" ::: "memory");
  __builtin_amdgcn_s_barrier();
  QK_COMPUTE(0, sA);
  ITER_END();

  for (int tt = 0; tt < NT; tt += 2) {
    {  // iter T = tt   (cur = sA, next = sB)
      const int T = tt;
      const int stg = (T + 3 < NT) ? (T + 3) : (NT - 1);
      ATTN_STAGE(stg, (T + 3) & 3);
      QK_COMPUTE(T + 1, sB);       // MFMA: QK of tile T+1 (landed by prev vmcnt(4))
      SM_PV_HALF(T, sA, 0);        // VALU softmax || PV MFMA
      SM_PV_HALF(T, sA, 1);
      ITER_END();
    }
    {  // iter T = tt+1 (cur = sB, next = sA)
      const int T = tt + 1;
      const int stg = (T + 3 < NT) ? (T + 3) : (NT - 1);
      ATTN_STAGE(stg, (T + 3) & 3);
      if (T + 1 < NT) QK_COMPUTE(T + 1, sA);
      SM_PV_HALF(T, sB, 0);
      SM_PV_HALF(T, sB, 1);
      ITER_END();
    }
  }
#undef ATTN_STAGE
#undef QK_COMPUTE
#undef SM_PV_HALF
#undef ITER_END

  // epilogue: acc_l[s][i] = l for q-row w*32 + s*16 + g*4 + i -> divide
#pragma unroll
  for (int s = 0; s < 2; ++s) {
#pragma unroll
    for (int i = 0; i < 4; ++i) {
      const float inv = 1.0f / acc_l[s][i];
      const size_t r = rowbase + qt * 128 + w * 32 + s * 16 + g * 4 + i;
#pragma unroll
      for (int df = 0; df < 4; ++df)
        ctx[r * DIMC + h * HD + df * 16 + lr] = (bf16)(acc_o[s][df][i] * inv);
    }
  }
}

// ---------------- launch ----------------
extern "C" void kernel_launch(void* const* d_in, const int* in_sizes, int n_in,
                              void* d_out, int out_size, void* d_ws, size_t ws_size,
                              hipStream_t stream) {
  const float* x    = (const float*)d_in[0];
  const float* mask = (const float*)d_in[1];
  const float* qw = (const float*)d_in[2]; const float* qb = (const float*)d_in[3];
  const float* kw = (const float*)d_in[4]; const float* kb = (const float*)d_in[5];
  const float* vw = (const float*)d_in[6]; const float* vb = (const float*)d_in[7];
  const float* ow = (const float*)d_in[8]; const float* ob = (const float*)d_in[9];
  float* out = (float*)d_out;

  // workspace layout (bf16 elements); ctx uses the (unwritten) V slot
  bf16* Xb  = (bf16*)d_ws;
  bf16* Wqb = Xb  + (size_t)MTOT * DIMC;
  bf16* Wkb = Wqb + (size_t)DIMC * DIMC;
  bf16* Wvb = Wkb + (size_t)DIMC * DIMC;
  bf16* Wob = Wvb + (size_t)DIMC * DIMC;
  bf16* Qb  = Wob + (size_t)DIMC * DIMC;
  bf16* Kb  = Qb  + (size_t)MTOT * DIMC;
  bf16* Cb  = Kb  + (size_t)MTOT * DIMC;   // ctx (V slot; V never materialized)
  bf16* Vt  = Cb  + (size_t)MTOT * DIMC;
  bf16* Mex = Vt  + (size_t)MTOT * DIMC;   // 4096 bf16

  // merged conversion + Mexp: 8192 blocks cover X/W, 4 extra cover mask
  prep_cvt<<<8196, 256, 0, stream>>>(x, qw, kw, vw, ow, mask,
                                     Xb, Wqb, Wkb, Wvb, Wob, Mex);

  // fused QKV projections: Q=(X Wq^T + bq)*0.125*log2e, K, V->Vt (scaled, transposed)
  gemm_bt<<<dim3(32, 8, 3), 128, 0, stream>>>(
      Xb, Wqb, Wkb, Wvb, qb, kb, vb, Qb, Kb, Vt, Mex, 0.125f * LOG2E);

  attn_fwd<<<512, 256, 0, stream>>>(Qb, Kb, Vt, Mex, Cb);

  // output projection (fp32 out), 128x64 tiles -> 512 blocks
  gemm_o<<<dim3(32, 16), 256, 0, stream>>>(Cb, Wob, ob, out);
}

// Round 21
// 106.445 us; speedup vs baseline: 1.0395x; 1.0395x over previous
//
#include <hip/hip_runtime.h>
#include <hip/hip_bf16.h>

typedef __bf16 bf16;
typedef __attribute__((ext_vector_type(8))) __bf16 bf16x8;
typedef __attribute__((ext_vector_type(4))) __bf16 bf16x4;
typedef __attribute__((ext_vector_type(4))) float f32x4;

#define GLOAD_LDS16(g, l) __builtin_amdgcn_global_load_lds( \
    (const __attribute__((address_space(1))) void*)(g),     \
    (__attribute__((address_space(3))) void*)(l), 16, 0, 0)

#if __has_builtin(__builtin_amdgcn_exp2f)
#define EXP2F(x) __builtin_amdgcn_exp2f(x)
#else
#define EXP2F(x) exp2f(x)
#endif

constexpr int MTOT = 4096;   // BS*QLEN
constexpr int DIMC = 1024;
constexpr int QL   = 2048;
constexpr int NH   = 16;
constexpr int HD   = 64;
constexpr float LOG2E = 1.44269504088896340736f;

// ---------------- merged prep: fp32->bf16 for X + 4 weights, and Mexp = exp(mask) ----
__global__ __launch_bounds__(256) void prep_cvt(
    const float* __restrict__ x,  const float* __restrict__ qw,
    const float* __restrict__ kw, const float* __restrict__ vw,
    const float* __restrict__ ow, const float* __restrict__ mask,
    bf16* __restrict__ Xb, bf16* __restrict__ Wq, bf16* __restrict__ Wk,
    bf16* __restrict__ Wv, bf16* __restrict__ Wo, bf16* __restrict__ Mexp)
{
  const long long bid = blockIdx.x;
  if (bid >= 8192) {   // Mexp: 2*2048 fp32 -> bf16 exp(mask)
    const int off = (int)(bid - 8192) * 1024 + threadIdx.x * 4;
    float4 f = *reinterpret_cast<const float4*>(mask + off);
    bf16x4 v;
    v[0] = (bf16)exp2f(f.x * LOG2E); v[1] = (bf16)exp2f(f.y * LOG2E);
    v[2] = (bf16)exp2f(f.z * LOG2E); v[3] = (bf16)exp2f(f.w * LOG2E);
    *reinterpret_cast<bf16x4*>(Mexp + off) = v;
    return;
  }
  const long long i = (bid * 256 + threadIdx.x) * 4;
  const long long nX = (long long)MTOT * DIMC;      // 4M
  const long long nW = (long long)DIMC * DIMC;      // 1M
  const float* src; bf16* dst; long long off;
  if      (i < nX)          { src = x;  dst = Xb; off = i; }
  else if (i < nX + nW)     { src = qw; dst = Wq; off = i - nX; }
  else if (i < nX + 2*nW)   { src = kw; dst = Wk; off = i - nX - nW; }
  else if (i < nX + 3*nW)   { src = vw; dst = Wv; off = i - nX - 2*nW; }
  else                      { src = ow; dst = Wo; off = i - nX - 3*nW; }
  float4 f = *reinterpret_cast<const float4*>(src + off);
  bf16x4 v;
  v[0] = (bf16)f.x; v[1] = (bf16)f.y; v[2] = (bf16)f.z; v[3] = (bf16)f.w;
  *reinterpret_cast<bf16x4*>(dst + off) = v;
}

// ---------------- QKV GEMM (bf16 out): C = (A W^T + bias) * scale ----
// 128 threads = 2 waves; wave w owns cols [w*64, +64) of the 128x128 tile and
// ALL 128 rows -> per kk: 8 A-frags + 4 B-frags feed 32 MFMAs (0.375 reads/MFMA).
// Single-buffer 32KB LDS; natural dispatch order (R20 XCD remap regressed:
// forced every XCD to stream ALL A-panels; natural x-fastest order already
// clusters A-reuse. REVERTED). Both-sides XOR swizzle (T2).
// z==2: tile TRANSPOSED to Vt, cols scaled by Mexp.
__global__ __launch_bounds__(128, 2) void gemm_bt(
    const bf16* __restrict__ A,
    const bf16* __restrict__ W0, const bf16* __restrict__ W1, const bf16* __restrict__ W2,
    const float* __restrict__ b0, const float* __restrict__ b1, const float* __restrict__ b2,
    bf16* __restrict__ D0, bf16* __restrict__ D1,
    bf16* __restrict__ VtOut, const bf16* __restrict__ Mexp, float scale0)
{
  __shared__ __align__(16) bf16 SMEM[16384];   // As | Bs, reused as T in z==2 epilogue
  bf16* As = SMEM;          // [128][64]
  bf16* Bs = SMEM + 8192;   // [128][64]

  const bf16* Bm; const float* bias; bf16* D = nullptr; float scale = 1.f;
  const int z = blockIdx.z;
  if (z == 0)      { Bm = W0; bias = b0; D = D0; scale = scale0; }
  else if (z == 1) { Bm = W1; bias = b1; D = D1; }
  else             { Bm = W2; bias = b2; }

  const int tid  = threadIdx.x;
  const int w    = tid >> 6, lane = tid & 63;
  const int gm0  = blockIdx.x * 128, gn0 = blockIdx.y * 128;
  const int wc   = w * 64;
  const int lr   = lane & 15;
  const int lkB  = (lane >> 4) * 16;                 // fragment byte col base
  const int srow = (w << 3) + (lane >> 3);           // staged row within a 16-row pass
  const int scolE = (((lane & 7) * 16) ^ (((lane >> 3) & 7) << 4)) >> 1;  // pre-swz src col

  f32x4 acc[8][4] = {};

  for (int kt = 0; kt < DIMC / 64; ++kt) {
    __syncthreads();
    const int k0 = kt * 64;
#pragma unroll
    for (int p = 0; p < 8; ++p) {
      const int r = p * 16 + srow;
      GLOAD_LDS16(A  + (size_t)(gm0 + r) * DIMC + k0 + scolE, &As[(p * 16 + (w << 3)) * 64]);
      GLOAD_LDS16(Bm + (size_t)(gn0 + r) * DIMC + k0 + scolE, &Bs[(p * 16 + (w << 3)) * 64]);
    }
    asm volatile("s_waitcnt vmcnt(0)" ::: "memory");
    __syncthreads();

#pragma unroll
    for (int kk = 0; kk < 2; ++kk) {
      bf16x8 af[8], bfv[4];
#pragma unroll
      for (int mf = 0; mf < 8; ++mf) {
        const int r = mf * 16 + lr;
        const int cE = ((kk * 64 + lkB) ^ ((r & 7) << 4)) >> 1;
        af[mf] = *reinterpret_cast<const bf16x8*>(&As[r * 64 + cE]);
      }
#pragma unroll
      for (int nf = 0; nf < 4; ++nf) {
        const int r = wc + nf * 16 + lr;
        const int cE = ((kk * 64 + lkB) ^ ((r & 7) << 4)) >> 1;
        bfv[nf] = *reinterpret_cast<const bf16x8*>(&Bs[r * 64 + cE]);
      }
#pragma unroll
      for (int mf = 0; mf < 8; ++mf)
#pragma unroll
        for (int nf = 0; nf < 4; ++nf)
          acc[mf][nf] = __builtin_amdgcn_mfma_f32_16x16x32_bf16(af[mf], bfv[nf], acc[mf][nf], 0, 0, 0);
    }
  }

  const int orow = (lane >> 4) * 4;

  if (z == 2) {
    // ---- transposed epilogue: acc -> T (swizzled LDS, b64 writes) -> Vt ----
    bf16* T = SMEM;                      // [128 c][128 r], r XOR-swizzled by (c&7)<<3
    __syncthreads();                     // all waves done reading As/Bs
#pragma unroll
    for (int mf = 0; mf < 8; ++mf) {
#pragma unroll
      for (int nf = 0; nf < 4; ++nf) {
        const int cl = wc + nf * 16 + lr;
        const float bv = bias[gn0 + cl];
        const int xx = (cl & 7) << 3;
        const int rl0 = mf * 16 + orow;            // 4-aligned; +i contiguous after XOR
        bf16x4 tv;
#pragma unroll
        for (int i = 0; i < 4; ++i) tv[i] = (bf16)(acc[mf][nf][i] + bv);
        *reinterpret_cast<bf16x4*>(&T[cl * 128 + (rl0 ^ xx)]) = tv;
      }
    }
    __syncthreads();
    // thread t: row c = tid (0..127), 16 b128 chunks over the 128 kv, staggered
    const int c   = tid;
    const int xx2 = (c & 7) << 3;
    const int cg  = gn0 + c;                       // global col in [0,1024)
    const int bb  = gm0 >> 11;                     // batch
    const int kvb = gm0 & 2047;                    // kv base within batch
    bf16* vtrow = VtOut + (((size_t)bb * 16 + (cg >> 6)) * 64 + (cg & 63)) * (size_t)QL
                  + kvb;
    const bf16* mrow = Mexp + (size_t)bb * QL + kvb;
    const int st = c & 15;
#pragma unroll
    for (int j = 0; j < 16; ++j) {
      const int jj = (j + st) & 15;
      bf16x8 vv = *reinterpret_cast<const bf16x8*>(&T[c * 128 + ((jj * 8) ^ xx2)]);
      const bf16x8 me = *reinterpret_cast<const bf16x8*>(mrow + jj * 8);
#pragma unroll
      for (int e = 0; e < 8; ++e) vv[e] = (bf16)((float)vv[e] * (float)me[e]);
      *reinterpret_cast<bf16x8*>(vtrow + jj * 8) = vv;
    }
    return;
  }

  // ---- normal epilogue (bf16) ----
#pragma unroll
  for (int mf = 0; mf < 8; ++mf) {
#pragma unroll
    for (int nf = 0; nf < 4; ++nf) {
      const int c = gn0 + wc + nf * 16 + lr;
      const float bv = bias[c];
#pragma unroll
      for (int i = 0; i < 4; ++i) {
        const int r = gm0 + mf * 16 + orow + i;
        D[(size_t)r * DIMC + c] = (bf16)((acc[mf][nf][i] + bv) * scale);
      }
    }
  }
}

// ---------------- Output projection GEMM (fp32 out): 128x64 tiles, swizzled ----
__global__ __launch_bounds__(256) void gemm_o(
    const bf16* __restrict__ A, const bf16* __restrict__ W,
    const float* __restrict__ bias, float* __restrict__ out)
{
  __shared__ __align__(16) bf16 As[128 * 64];
  __shared__ __align__(16) bf16 Bs[64 * 64];

  const int tid  = threadIdx.x;
  const int w    = tid >> 6, lane = tid & 63;
  const int gm0  = blockIdx.x * 128, gn0 = blockIdx.y * 64;
  const int wr   = (w >> 1) * 64, wc = (w & 1) * 32;
  const int lr   = lane & 15;
  const int lkB  = (lane >> 4) * 16;
  const int srow = (w << 3) + (lane >> 3);
  const int scolE = (((lane & 7) * 16) ^ ((lane >> 3) << 4)) >> 1;

  f32x4 acc[4][2] = {};

  for (int kt = 0; kt < DIMC / 64; ++kt) {
    __syncthreads();
    const int k0 = kt * 64;
#pragma unroll
    for (int p = 0; p < 4; ++p) {
      const int r = p * 32 + srow;
      GLOAD_LDS16(A + (size_t)(gm0 + r) * DIMC + k0 + scolE, &As[(p * 32 + (w << 3)) * 64]);
    }
#pragma unroll
    for (int p = 0; p < 2; ++p) {
      const int r = p * 32 + srow;
      GLOAD_LDS16(W + (size_t)(gn0 + r) * DIMC + k0 + scolE, &Bs[(p * 32 + (w << 3)) * 64]);
    }
    asm volatile("s_waitcnt vmcnt(0)" ::: "memory");
    __syncthreads();

#pragma unroll
    for (int kk = 0; kk < 2; ++kk) {
      bf16x8 af[4], bfv[2];
#pragma unroll
      for (int mf = 0; mf < 4; ++mf) {
        const int r = wr + mf * 16 + lr;
        const int cE = ((kk * 64 + lkB) ^ ((r & 7) << 4)) >> 1;
        af[mf] = *reinterpret_cast<const bf16x8*>(&As[r * 64 + cE]);
      }
#pragma unroll
      for (int nf = 0; nf < 2; ++nf) {
        const int r = wc + nf * 16 + lr;
        const int cE = ((kk * 64 + lkB) ^ ((r & 7) << 4)) >> 1;
        bfv[nf] = *reinterpret_cast<const bf16x8*>(&Bs[r * 64 + cE]);
      }
#pragma unroll
      for (int mf = 0; mf < 4; ++mf)
#pragma unroll
        for (int nf = 0; nf < 2; ++nf)
          acc[mf][nf] = __builtin_amdgcn_mfma_f32_16x16x32_bf16(af[mf], bfv[nf], acc[mf][nf], 0, 0, 0);
    }
  }

  const int orow = (lane >> 4) * 4;
#pragma unroll
  for (int mf = 0; mf < 4; ++mf) {
#pragma unroll
    for (int nf = 0; nf < 2; ++nf) {
      const int c = gn0 + wc + nf * 16 + lr;
      const float bv = bias[c];
#pragma unroll
      for (int i = 0; i < 4; ++i) {
        const int r = gm0 + wr + mf * 16 + orow + i;
        out[(size_t)r * DIMC + c] = acc[mf][nf][i] + bv;
      }
    }
  }
}

// ---------------- Flash attention: 2 q-sets/wave + 2-state cross-tile pipeline ----
// (unchanged — attn is at its LDS-pipe structural plateau ~54 us)
__global__ __launch_bounds__(256, 2) void attn_fwd(
    const bf16* __restrict__ Q, const bf16* __restrict__ K, const bf16* __restrict__ Vt,
    const bf16* __restrict__ Mexp, bf16* __restrict__ ctx)
{
  __shared__ __align__(16) bf16 Kls[4 * 4096];
  __shared__ __align__(16) bf16 Vls[4 * 4096];
  __shared__ __align__(16) bf16 Ps[4][2 * 16 * 36];   // per wave, per q-set [16][36]

  const int tid = threadIdx.x, w = tid >> 6, lane = tid & 63;
  const int bid = blockIdx.x;
  const int logical = (bid & 7) * 64 + (bid >> 3);    // bijective: 512 = 8*64
  const int qt = logical & 15, bh = logical >> 4;     // 4 bh per XCD -> 2MB KV in L2
  const int b = bh >> 4, h = bh & 15;
  const size_t rowbase = (size_t)b * QL;
  const int lr = lane & 15, g = lane >> 4;
  const int lkB = g * 16;   // byte col base of this lane's 16B fragment chunk

  // Q fragments (B operand after swap): 2 sets, rows qt*128 + w*32 + s*16 + lr
  bf16x8 aq[2][2];
#pragma unroll
  for (int s = 0; s < 2; ++s) {
    const bf16* qp = Q + (rowbase + qt * 128 + w * 32 + s * 16 + lr) * DIMC + h * HD + g * 8;
    aq[s][0] = *reinterpret_cast<const bf16x8*>(qp);
    aq[s][1] = *reinterpret_cast<const bf16x8*>(qp + 32);
  }

  // staging geometry: 256 threads, two 16B chunks each per 8KB tile (4 loads total).
  int g_row[2], g_colE[2];
#pragma unroll
  for (int s2 = 0; s2 < 2; ++s2) {
    const int ci = s2 * 256 + tid;
    const int row = ci >> 3;
    g_row[s2]  = row;
    g_colE[s2] = (((ci & 7) * 16) ^ ((row & 7) << 4)) >> 1;
  }
  const bf16* Kt0 = K  + rowbase * DIMC + h * HD;
  const bf16* Vt0 = Vt + (size_t)bh * HD * QL;
  const bf16* MexpP = Mexp + rowbase;

#define ATTN_STAGE(tt, bb) do {                                               \
    _Pragma("unroll")                                                         \
    for (int s2 = 0; s2 < 2; ++s2) {                                          \
      GLOAD_LDS16(Kt0 + (size_t)((tt) * 64 + g_row[s2]) * DIMC + g_colE[s2],  \
                  &Kls[(bb) * 4096 + (s2 * 256 + tid) * 8]);                  \
      GLOAD_LDS16(Vt0 + (size_t)g_row[s2] * QL + (tt) * 64 + g_colE[s2],      \
                  &Vls[(bb) * 4096 + (s2 * 256 + tid) * 8]);                  \
    }                                                                         \
  } while (0)

  const f32x4 zf4 = {0.f, 0.f, 0.f, 0.f};

// QK for both q-sets into state SACC[2][4]; K frags read ONCE, used 2x.
#define QK_COMPUTE(TT, SACC) do {                                             \
    const bf16* Kb = &Kls[((TT) & 3) * 4096];                                 \
    bf16x8 bk0[4], bk1[4];                                                    \
    _Pragma("unroll")                                                         \
    for (int nf = 0; nf < 4; ++nf) {                                          \
      const int r = nf * 16 + lr;                                             \
      const int c0 = ((lkB)      ^ ((r & 7) << 4)) >> 1;                      \
      const int c1 = ((64 + lkB) ^ ((r & 7) << 4)) >> 1;                      \
      bk0[nf] = *reinterpret_cast<const bf16x8*>(&Kb[r * 64 + c0]);           \
      bk1[nf] = *reinterpret_cast<const bf16x8*>(&Kb[r * 64 + c1]);           \
    }                                                                         \
    __builtin_amdgcn_s_setprio(1);                                            \
    _Pragma("unroll")                                                         \
    for (int s = 0; s < 2; ++s)                                               \
      _Pragma("unroll")                                                       \
      for (int nf = 0; nf < 4; ++nf)                                          \
        SACC[s][nf] = __builtin_amdgcn_mfma_f32_16x16x32_bf16(bk0[nf], aq[s][0], zf4, 0, 0, 0); \
    _Pragma("unroll")                                                         \
    for (int s = 0; s < 2; ++s)                                               \
      _Pragma("unroll")                                                       \
      for (int nf = 0; nf < 4; ++nf)                                          \
        SACC[s][nf] = __builtin_amdgcn_mfma_f32_16x16x32_bf16(bk1[nf], aq[s][1], SACC[s][nf], 0, 0, 0); \
    __builtin_amdgcn_s_setprio(0);                                            \
  } while (0)

// softmax + PV for tile TT from state SC, one kk-half.
#define SM_PV_HALF(TT, SC, HALF) do {                                         \
    _Pragma("unroll")                                                         \
    for (int s = 0; s < 2; ++s) {                                             \
      _Pragma("unroll")                                                       \
      for (int nn = 0; nn < 2; ++nn) {                                        \
        const int nf = (HALF) * 2 + nn;                                       \
        const float p0 = EXP2F(SC[s][nf][0]);                                 \
        const float p1 = EXP2F(SC[s][nf][1]);                                 \
        const float p2 = EXP2F(SC[s][nf][2]);                                 \
        const float p3 = EXP2F(SC[s][nf][3]);                                 \
        bf16x4 pv;                                                            \
        pv[0] = (bf16)p0; pv[1] = (bf16)p1; pv[2] = (bf16)p2; pv[3] = (bf16)p3; \
        *reinterpret_cast<bf16x4*>(&Ps[w][s * 576 + lr * 36 + nn * 16 + g * 4]) = pv; \
      }                                                                       \
    }                                                                         \
    const bf16x8 mfrag = *reinterpret_cast<const bf16x8*>(                    \
        MexpP + (TT) * 64 + (HALF) * 32 + g * 8);                             \
    const bf16* Vb = &Vls[((TT) & 3) * 4096];                                 \
    bf16x8 bv[4];                                                             \
    _Pragma("unroll")                                                         \
    for (int df = 0; df < 4; ++df) {                                          \
      const int r = df * 16 + lr;                                             \
      const int cE = (((HALF) * 64 + lkB) ^ ((r & 7) << 4)) >> 1;             \
      bv[df] = *reinterpret_cast<const bf16x8*>(&Vb[r * 64 + cE]);            \
    }                                                                         \
    bf16x8 ap0, ap1;                                                          \
    {                                                                         \
      const bf16x4 lo0 = *reinterpret_cast<const bf16x4*>(&Ps[w][0 * 576 + lr * 36 + g * 8]); \
      const bf16x4 hi0 = *reinterpret_cast<const bf16x4*>(&Ps[w][0 * 576 + lr * 36 + g * 8 + 4]); \
      const bf16x4 lo1 = *reinterpret_cast<const bf16x4*>(&Ps[w][1 * 576 + lr * 36 + g * 8]); \
      const bf16x4 hi1 = *reinterpret_cast<const bf16x4*>(&Ps[w][1 * 576 + lr * 36 + g * 8 + 4]); \
      _Pragma("unroll")                                                       \
      for (int j = 0; j < 4; ++j) {                                           \
        ap0[j] = lo0[j]; ap0[4 + j] = hi0[j];                                 \
        ap1[j] = lo1[j]; ap1[4 + j] = hi1[j];                                 \
      }                                                                       \
    }                                                                         \
    __builtin_amdgcn_s_setprio(1);                                            \
    acc_l[0] = __builtin_amdgcn_mfma_f32_16x16x32_bf16(ap0, mfrag, acc_l[0], 0, 0, 0); \
    acc_l[1] = __builtin_amdgcn_mfma_f32_16x16x32_bf16(ap1, mfrag, acc_l[1], 0, 0, 0); \
    _Pragma("unroll")                                                         \
    for (int df = 0; df < 4; ++df)                                            \
      acc_o[0][df] = __builtin_amdgcn_mfma_f32_16x16x32_bf16(ap0, bv[df], acc_o[0][df], 0, 0, 0); \
    _Pragma("unroll")                                                         \
    for (int df = 0; df < 4; ++df)                                            \
      acc_o[1][df] = __builtin_amdgcn_mfma_f32_16x16x32_bf16(ap1, bv[df], acc_o[1][df], 0, 0, 0); \
    __builtin_amdgcn_s_setprio(0);                                            \
  } while (0)

// counted wait: the newest stage (4 loads) stays in flight; tile T+2 landed.
#define ITER_END() do {                                                       \
    asm volatile("s_waitcnt vmcnt(4) lgkmcnt(0)" ::: "memory");               \
    __builtin_amdgcn_s_barrier();                                             \
    __builtin_amdgcn_sched_barrier(0);                                        \
  } while (0)

  f32x4 acc_l[2] = {};
  f32x4 acc_o[2][4] = {};
  f32x4 sA[2][4], sB[2][4];

  constexpr int NT = QL / 64;   // 32 (even)

  // prologue: stage tiles 0-2 (12 loads); vmcnt(8) -> tile 0 landed; QK(0)->sA;
  // ITER_END vmcnt(4) -> tile 1 landed (tile 2's loads stay in flight).
  ATTN_STAGE(0, 0);
  ATTN_STAGE(1, 1);
  ATTN_STAGE(2, 2);
  asm volatile("s_waitcnt vmcnt(8)" ::: "memory");
  __builtin_amdgcn_s_barrier();
  QK_COMPUTE(0, sA);
  ITER_END();

  for (int tt = 0; tt < NT; tt += 2) {
    {  // iter T = tt   (cur = sA, next = sB)
      const int T = tt;
      const int stg = (T + 3 < NT) ? (T + 3) : (NT - 1);
      ATTN_STAGE(stg, (T + 3) & 3);
      QK_COMPUTE(T + 1, sB);       // MFMA: QK of tile T+1 (landed by prev vmcnt(4))
      SM_PV_HALF(T, sA, 0);        // VALU softmax || PV MFMA
      SM_PV_HALF(T, sA, 1);
      ITER_END();
    }
    {  // iter T = tt+1 (cur = sB, next = sA)
      const int T = tt + 1;
      const int stg = (T + 3 < NT) ? (T + 3) : (NT - 1);
      ATTN_STAGE(stg, (T + 3) & 3);
      if (T + 1 < NT) QK_COMPUTE(T + 1, sA);
      SM_PV_HALF(T, sB, 0);
      SM_PV_HALF(T, sB, 1);
      ITER_END();
    }
  }
#undef ATTN_STAGE
#undef QK_COMPUTE
#undef SM_PV_HALF
#undef ITER_END

  // epilogue: acc_l[s][i] = l for q-row w*32 + s*16 + g*4 + i -> divide
#pragma unroll
  for (int s = 0; s < 2; ++s) {
#pragma unroll
    for (int i = 0; i < 4; ++i) {
      const float inv = 1.0f / acc_l[s][i];
      const size_t r = rowbase + qt * 128 + w * 32 + s * 16 + g * 4 + i;
#pragma unroll
      for (int df = 0; df < 4; ++df)
        ctx[r * DIMC + h * HD + df * 16 + lr] = (bf16)(acc_o[s][df][i] * inv);
    }
  }
}

// ---------------- launch ----------------
extern "C" void kernel_launch(void* const* d_in, const int* in_sizes, int n_in,
                              void* d_out, int out_size, void* d_ws, size_t ws_size,
                              hipStream_t stream) {
  const float* x    = (const float*)d_in[0];
  const float* mask = (const float*)d_in[1];
  const float* qw = (const float*)d_in[2]; const float* qb = (const float*)d_in[3];
  const float* kw = (const float*)d_in[4]; const float* kb = (const float*)d_in[5];
  const float* vw = (const float*)d_in[6]; const float* vb = (const float*)d_in[7];
  const float* ow = (const float*)d_in[8]; const float* ob = (const float*)d_in[9];
  float* out = (float*)d_out;

  // workspace layout (bf16 elements); ctx uses the (unwritten) V slot
  bf16* Xb  = (bf16*)d_ws;
  bf16* Wqb = Xb  + (size_t)MTOT * DIMC;
  bf16* Wkb = Wqb + (size_t)DIMC * DIMC;
  bf16* Wvb = Wkb + (size_t)DIMC * DIMC;
  bf16* Wob = Wvb + (size_t)DIMC * DIMC;
  bf16* Qb  = Wob + (size_t)DIMC * DIMC;
  bf16* Kb  = Qb  + (size_t)MTOT * DIMC;
  bf16* Cb  = Kb  + (size_t)MTOT * DIMC;   // ctx (V slot; V never materialized)
  bf16* Vt  = Cb  + (size_t)MTOT * DIMC;
  bf16* Mex = Vt  + (size_t)MTOT * DIMC;   // 4096 bf16

  // merged conversion + Mexp: 8192 blocks cover X/W, 4 extra cover mask
  prep_cvt<<<8196, 256, 0, stream>>>(x, qw, kw, vw, ow, mask,
                                     Xb, Wqb, Wkb, Wvb, Wob, Mex);

  // fused QKV projections: Q=(X Wq^T + bq)*0.125*log2e, K, V->Vt (scaled, transposed)
  gemm_bt<<<dim3(32, 8, 3), 128, 0, stream>>>(
      Xb, Wqb, Wkb, Wvb, qb, kb, vb, Qb, Kb, Vt, Mex, 0.125f * LOG2E);

  attn_fwd<<<512, 256, 0, stream>>>(Qb, Kb, Vt, Mex, Cb);

  // output projection (fp32 out), 128x64 tiles -> 512 blocks
  gemm_o<<<dim3(32, 16), 256, 0, stream>>>(Cb, Wob, ob, out);
}

// Round 22
// 103.438 us; speedup vs baseline: 1.0698x; 1.0291x over previous
//
#include <hip/hip_runtime.h>
#include <hip/hip_bf16.h>

typedef __bf16 bf16;
typedef __attribute__((ext_vector_type(8))) __bf16 bf16x8;
typedef __attribute__((ext_vector_type(4))) __bf16 bf16x4;
typedef __attribute__((ext_vector_type(4))) float f32x4;

#define GLOAD_LDS16(g, l) __builtin_amdgcn_global_load_lds( \
    (const __attribute__((address_space(1))) void*)(g),     \
    (__attribute__((address_space(3))) void*)(l), 16, 0, 0)

#if __has_builtin(__builtin_amdgcn_exp2f)
#define EXP2F(x) __builtin_amdgcn_exp2f(x)
#else
#define EXP2F(x) exp2f(x)
#endif

constexpr int MTOT = 4096;   // BS*QLEN
constexpr int DIMC = 1024;
constexpr int QL   = 2048;
constexpr int NH   = 16;
constexpr int HD   = 64;
constexpr float LOG2E = 1.44269504088896340736f;

// ---------------- merged prep: fp32->bf16 for X + 4 weights, and Mexp = exp(mask) ----
__global__ __launch_bounds__(256) void prep_cvt(
    const float* __restrict__ x,  const float* __restrict__ qw,
    const float* __restrict__ kw, const float* __restrict__ vw,
    const float* __restrict__ ow, const float* __restrict__ mask,
    bf16* __restrict__ Xb, bf16* __restrict__ Wq, bf16* __restrict__ Wk,
    bf16* __restrict__ Wv, bf16* __restrict__ Wo, bf16* __restrict__ Mexp)
{
  const long long bid = blockIdx.x;
  if (bid >= 8192) {   // Mexp: 2*2048 fp32 -> bf16 exp(mask)
    const int off = (int)(bid - 8192) * 1024 + threadIdx.x * 4;
    float4 f = *reinterpret_cast<const float4*>(mask + off);
    bf16x4 v;
    v[0] = (bf16)exp2f(f.x * LOG2E); v[1] = (bf16)exp2f(f.y * LOG2E);
    v[2] = (bf16)exp2f(f.z * LOG2E); v[3] = (bf16)exp2f(f.w * LOG2E);
    *reinterpret_cast<bf16x4*>(Mexp + off) = v;
    return;
  }
  const long long i = (bid * 256 + threadIdx.x) * 4;
  const long long nX = (long long)MTOT * DIMC;      // 4M
  const long long nW = (long long)DIMC * DIMC;      // 1M
  const float* src; bf16* dst; long long off;
  if      (i < nX)          { src = x;  dst = Xb; off = i; }
  else if (i < nX + nW)     { src = qw; dst = Wq; off = i - nX; }
  else if (i < nX + 2*nW)   { src = kw; dst = Wk; off = i - nX - nW; }
  else if (i < nX + 3*nW)   { src = vw; dst = Wv; off = i - nX - 2*nW; }
  else                      { src = ow; dst = Wo; off = i - nX - 3*nW; }
  float4 f = *reinterpret_cast<const float4*>(src + off);
  bf16x4 v;
  v[0] = (bf16)f.x; v[1] = (bf16)f.y; v[2] = (bf16)f.z; v[3] = (bf16)f.w;
  *reinterpret_cast<bf16x4*>(dst + off) = v;
}

// ---------------- QKV GEMM (bf16 out): C = (A W^T + bias) * scale ----
// 128 threads = 2 waves; wave w owns cols [w*64, +64) of the 128x128 tile and
// ALL 128 rows -> per kk: 8 A-frags + 4 B-frags feed 32 MFMAs (0.375 reads/MFMA).
// Single-buffer 32KB LDS; natural dispatch order. Both-sides XOR swizzle (T2).
// z==2: tile TRANSPOSED to Vt, cols scaled by Mexp.
__global__ __launch_bounds__(128, 2) void gemm_bt(
    const bf16* __restrict__ A,
    const bf16* __restrict__ W0, const bf16* __restrict__ W1, const bf16* __restrict__ W2,
    const float* __restrict__ b0, const float* __restrict__ b1, const float* __restrict__ b2,
    bf16* __restrict__ D0, bf16* __restrict__ D1,
    bf16* __restrict__ VtOut, const bf16* __restrict__ Mexp, float scale0)
{
  __shared__ __align__(16) bf16 SMEM[16384];   // As | Bs, reused as T in z==2 epilogue
  bf16* As = SMEM;          // [128][64]
  bf16* Bs = SMEM + 8192;   // [128][64]

  const bf16* Bm; const float* bias; bf16* D = nullptr; float scale = 1.f;
  const int z = blockIdx.z;
  if (z == 0)      { Bm = W0; bias = b0; D = D0; scale = scale0; }
  else if (z == 1) { Bm = W1; bias = b1; D = D1; }
  else             { Bm = W2; bias = b2; }

  const int tid  = threadIdx.x;
  const int w    = tid >> 6, lane = tid & 63;
  const int gm0  = blockIdx.x * 128, gn0 = blockIdx.y * 128;
  const int wc   = w * 64;
  const int lr   = lane & 15;
  const int lkB  = (lane >> 4) * 16;                 // fragment byte col base
  const int srow = (w << 3) + (lane >> 3);           // staged row within a 16-row pass
  const int scolE = (((lane & 7) * 16) ^ (((lane >> 3) & 7) << 4)) >> 1;  // pre-swz src col

  f32x4 acc[8][4] = {};

  for (int kt = 0; kt < DIMC / 64; ++kt) {
    __syncthreads();
    const int k0 = kt * 64;
#pragma unroll
    for (int p = 0; p < 8; ++p) {
      const int r = p * 16 + srow;
      GLOAD_LDS16(A  + (size_t)(gm0 + r) * DIMC + k0 + scolE, &As[(p * 16 + (w << 3)) * 64]);
      GLOAD_LDS16(Bm + (size_t)(gn0 + r) * DIMC + k0 + scolE, &Bs[(p * 16 + (w << 3)) * 64]);
    }
    asm volatile("s_waitcnt vmcnt(0)" ::: "memory");
    __syncthreads();

#pragma unroll
    for (int kk = 0; kk < 2; ++kk) {
      bf16x8 af[8], bfv[4];
#pragma unroll
      for (int mf = 0; mf < 8; ++mf) {
        const int r = mf * 16 + lr;
        const int cE = ((kk * 64 + lkB) ^ ((r & 7) << 4)) >> 1;
        af[mf] = *reinterpret_cast<const bf16x8*>(&As[r * 64 + cE]);
      }
#pragma unroll
      for (int nf = 0; nf < 4; ++nf) {
        const int r = wc + nf * 16 + lr;
        const int cE = ((kk * 64 + lkB) ^ ((r & 7) << 4)) >> 1;
        bfv[nf] = *reinterpret_cast<const bf16x8*>(&Bs[r * 64 + cE]);
      }
#pragma unroll
      for (int mf = 0; mf < 8; ++mf)
#pragma unroll
        for (int nf = 0; nf < 4; ++nf)
          acc[mf][nf] = __builtin_amdgcn_mfma_f32_16x16x32_bf16(af[mf], bfv[nf], acc[mf][nf], 0, 0, 0);
    }
  }

  const int orow = (lane >> 4) * 4;

  if (z == 2) {
    // ---- transposed epilogue: acc -> T (swizzled LDS, b64 writes) -> Vt ----
    bf16* T = SMEM;                      // [128 c][128 r], r XOR-swizzled by (c&7)<<3
    __syncthreads();                     // all waves done reading As/Bs
#pragma unroll
    for (int mf = 0; mf < 8; ++mf) {
#pragma unroll
      for (int nf = 0; nf < 4; ++nf) {
        const int cl = wc + nf * 16 + lr;
        const float bv = bias[gn0 + cl];
        const int xx = (cl & 7) << 3;
        const int rl0 = mf * 16 + orow;            // 4-aligned; +i contiguous after XOR
        bf16x4 tv;
#pragma unroll
        for (int i = 0; i < 4; ++i) tv[i] = (bf16)(acc[mf][nf][i] + bv);
        *reinterpret_cast<bf16x4*>(&T[cl * 128 + (rl0 ^ xx)]) = tv;
      }
    }
    __syncthreads();
    // thread t: row c = tid (0..127), 16 b128 chunks over the 128 kv, staggered
    const int c   = tid;
    const int xx2 = (c & 7) << 3;
    const int cg  = gn0 + c;                       // global col in [0,1024)
    const int bb  = gm0 >> 11;                     // batch
    const int kvb = gm0 & 2047;                    // kv base within batch
    bf16* vtrow = VtOut + (((size_t)bb * 16 + (cg >> 6)) * 64 + (cg & 63)) * (size_t)QL
                  + kvb;
    const bf16* mrow = Mexp + (size_t)bb * QL + kvb;
    const int st = c & 15;
#pragma unroll
    for (int j = 0; j < 16; ++j) {
      const int jj = (j + st) & 15;
      bf16x8 vv = *reinterpret_cast<const bf16x8*>(&T[c * 128 + ((jj * 8) ^ xx2)]);
      const bf16x8 me = *reinterpret_cast<const bf16x8*>(mrow + jj * 8);
#pragma unroll
      for (int e = 0; e < 8; ++e) vv[e] = (bf16)((float)vv[e] * (float)me[e]);
      *reinterpret_cast<bf16x8*>(vtrow + jj * 8) = vv;
    }
    return;
  }

  // ---- normal epilogue (bf16) ----
#pragma unroll
  for (int mf = 0; mf < 8; ++mf) {
#pragma unroll
    for (int nf = 0; nf < 4; ++nf) {
      const int c = gn0 + wc + nf * 16 + lr;
      const float bv = bias[c];
#pragma unroll
      for (int i = 0; i < 4; ++i) {
        const int r = gm0 + mf * 16 + orow + i;
        D[(size_t)r * DIMC + c] = (bf16)((acc[mf][nf][i] + bv) * scale);
      }
    }
  }
}

// ---------------- Output projection GEMM (fp32 out): 128x64 tiles, swizzled ----
__global__ __launch_bounds__(256) void gemm_o(
    const bf16* __restrict__ A, const bf16* __restrict__ W,
    const float* __restrict__ bias, float* __restrict__ out)
{
  __shared__ __align__(16) bf16 As[128 * 64];
  __shared__ __align__(16) bf16 Bs[64 * 64];

  const int tid  = threadIdx.x;
  const int w    = tid >> 6, lane = tid & 63;
  const int gm0  = blockIdx.x * 128, gn0 = blockIdx.y * 64;
  const int wr   = (w >> 1) * 64, wc = (w & 1) * 32;
  const int lr   = lane & 15;
  const int lkB  = (lane >> 4) * 16;
  const int srow = (w << 3) + (lane >> 3);
  const int scolE = (((lane & 7) * 16) ^ ((lane >> 3) << 4)) >> 1;

  f32x4 acc[4][2] = {};

  for (int kt = 0; kt < DIMC / 64; ++kt) {
    __syncthreads();
    const int k0 = kt * 64;
#pragma unroll
    for (int p = 0; p < 4; ++p) {
      const int r = p * 32 + srow;
      GLOAD_LDS16(A + (size_t)(gm0 + r) * DIMC + k0 + scolE, &As[(p * 32 + (w << 3)) * 64]);
    }
#pragma unroll
    for (int p = 0; p < 2; ++p) {
      const int r = p * 32 + srow;
      GLOAD_LDS16(W + (size_t)(gn0 + r) * DIMC + k0 + scolE, &Bs[(p * 32 + (w << 3)) * 64]);
    }
    asm volatile("s_waitcnt vmcnt(0)" ::: "memory");
    __syncthreads();

#pragma unroll
    for (int kk = 0; kk < 2; ++kk) {
      bf16x8 af[4], bfv[2];
#pragma unroll
      for (int mf = 0; mf < 4; ++mf) {
        const int r = wr + mf * 16 + lr;
        const int cE = ((kk * 64 + lkB) ^ ((r & 7) << 4)) >> 1;
        af[mf] = *reinterpret_cast<const bf16x8*>(&As[r * 64 + cE]);
      }
#pragma unroll
      for (int nf = 0; nf < 2; ++nf) {
        const int r = wc + nf * 16 + lr;
        const int cE = ((kk * 64 + lkB) ^ ((r & 7) << 4)) >> 1;
        bfv[nf] = *reinterpret_cast<const bf16x8*>(&Bs[r * 64 + cE]);
      }
#pragma unroll
      for (int mf = 0; mf < 4; ++mf)
#pragma unroll
        for (int nf = 0; nf < 2; ++nf)
          acc[mf][nf] = __builtin_amdgcn_mfma_f32_16x16x32_bf16(af[mf], bfv[nf], acc[mf][nf], 0, 0, 0);
    }
  }

  const int orow = (lane >> 4) * 4;
#pragma unroll
  for (int mf = 0; mf < 4; ++mf) {
#pragma unroll
    for (int nf = 0; nf < 2; ++nf) {
      const int c = gn0 + wc + nf * 16 + lr;
      const float bv = bias[c];
#pragma unroll
      for (int i = 0; i < 4; ++i) {
        const int r = gm0 + wr + mf * 16 + orow + i;
        out[(size_t)r * DIMC + c] = acc[mf][nf][i] + bv;
      }
    }
  }
}

// ---------------- Flash attention: 2 q-sets/wave, PAIR-processed tiles ----
// 256 threads = 4 waves; wave w owns q rows [qt*128 + w*32, +32) as 2 sets of 16.
// PAIR loop: quad-buffer holds 2 landed tiles; per iter stage the NEXT pair,
// QK both tiles (sA,sB), softmax+PV both, ONE drain+barrier -> 17 barriers
// instead of 33 (per-tile sync overhead halved; drain covered by ~2 tiles of
// compute issued after the stage). K/V frag reads shared by both q-sets.
// l and O accumulate on the matrix pipe (Mexp B-operand). LDS 73 KB, 2 blk/CU.
__global__ __launch_bounds__(256, 2) void attn_fwd(
    const bf16* __restrict__ Q, const bf16* __restrict__ K, const bf16* __restrict__ Vt,
    const bf16* __restrict__ Mexp, bf16* __restrict__ ctx)
{
  __shared__ __align__(16) bf16 Kls[4 * 4096];
  __shared__ __align__(16) bf16 Vls[4 * 4096];
  __shared__ __align__(16) bf16 Ps[4][2 * 16 * 36];   // per wave, per q-set [16][36]

  const int tid = threadIdx.x, w = tid >> 6, lane = tid & 63;
  const int bid = blockIdx.x;
  const int logical = (bid & 7) * 64 + (bid >> 3);    // bijective: 512 = 8*64
  const int qt = logical & 15, bh = logical >> 4;     // 4 bh per XCD -> 2MB KV in L2
  const int b = bh >> 4, h = bh & 15;
  const size_t rowbase = (size_t)b * QL;
  const int lr = lane & 15, g = lane >> 4;
  const int lkB = g * 16;   // byte col base of this lane's 16B fragment chunk

  // Q fragments (B operand after swap): 2 sets, rows qt*128 + w*32 + s*16 + lr
  bf16x8 aq[2][2];
#pragma unroll
  for (int s = 0; s < 2; ++s) {
    const bf16* qp = Q + (rowbase + qt * 128 + w * 32 + s * 16 + lr) * DIMC + h * HD + g * 8;
    aq[s][0] = *reinterpret_cast<const bf16x8*>(qp);
    aq[s][1] = *reinterpret_cast<const bf16x8*>(qp + 32);
  }

  // staging geometry: 256 threads, two 16B chunks each per 8KB tile (4 loads total).
  int g_row[2], g_colE[2];
#pragma unroll
  for (int s2 = 0; s2 < 2; ++s2) {
    const int ci = s2 * 256 + tid;
    const int row = ci >> 3;
    g_row[s2]  = row;
    g_colE[s2] = (((ci & 7) * 16) ^ ((row & 7) << 4)) >> 1;
  }
  const bf16* Kt0 = K  + rowbase * DIMC + h * HD;
  const bf16* Vt0 = Vt + (size_t)bh * HD * QL;
  const bf16* MexpP = Mexp + rowbase;

#define ATTN_STAGE(tt, bb) do {                                               \
    _Pragma("unroll")                                                         \
    for (int s2 = 0; s2 < 2; ++s2) {                                          \
      GLOAD_LDS16(Kt0 + (size_t)((tt) * 64 + g_row[s2]) * DIMC + g_colE[s2],  \
                  &Kls[(bb) * 4096 + (s2 * 256 + tid) * 8]);                  \
      GLOAD_LDS16(Vt0 + (size_t)g_row[s2] * QL + (tt) * 64 + g_colE[s2],      \
                  &Vls[(bb) * 4096 + (s2 * 256 + tid) * 8]);                  \
    }                                                                         \
  } while (0)

  const f32x4 zf4 = {0.f, 0.f, 0.f, 0.f};

// QK for both q-sets into state SACC[2][4]; K frags read ONCE, used 2x.
#define QK_COMPUTE(TT, SACC) do {                                             \
    const bf16* Kb = &Kls[((TT) & 3) * 4096];                                 \
    bf16x8 bk0[4], bk1[4];                                                    \
    _Pragma("unroll")                                                         \
    for (int nf = 0; nf < 4; ++nf) {                                          \
      const int r = nf * 16 + lr;                                             \
      const int c0 = ((lkB)      ^ ((r & 7) << 4)) >> 1;                      \
      const int c1 = ((64 + lkB) ^ ((r & 7) << 4)) >> 1;                      \
      bk0[nf] = *reinterpret_cast<const bf16x8*>(&Kb[r * 64 + c0]);           \
      bk1[nf] = *reinterpret_cast<const bf16x8*>(&Kb[r * 64 + c1]);           \
    }                                                                         \
    __builtin_amdgcn_s_setprio(1);                                            \
    _Pragma("unroll")                                                         \
    for (int s = 0; s < 2; ++s)                                               \
      _Pragma("unroll")                                                       \
      for (int nf = 0; nf < 4; ++nf)                                          \
        SACC[s][nf] = __builtin_amdgcn_mfma_f32_16x16x32_bf16(bk0[nf], aq[s][0], zf4, 0, 0, 0); \
    _Pragma("unroll")                                                         \
    for (int s = 0; s < 2; ++s)                                               \
      _Pragma("unroll")                                                       \
      for (int nf = 0; nf < 4; ++nf)                                          \
        SACC[s][nf] = __builtin_amdgcn_mfma_f32_16x16x32_bf16(bk1[nf], aq[s][1], SACC[s][nf], 0, 0, 0); \
    __builtin_amdgcn_s_setprio(0);                                            \
  } while (0)

// softmax + PV for tile TT from state SC, one kk-half.
#define SM_PV_HALF(TT, SC, HALF) do {                                         \
    _Pragma("unroll")                                                         \
    for (int s = 0; s < 2; ++s) {                                             \
      _Pragma("unroll")                                                       \
      for (int nn = 0; nn < 2; ++nn) {                                        \
        const int nf = (HALF) * 2 + nn;                                       \
        const float p0 = EXP2F(SC[s][nf][0]);                                 \
        const float p1 = EXP2F(SC[s][nf][1]);                                 \
        const float p2 = EXP2F(SC[s][nf][2]);                                 \
        const float p3 = EXP2F(SC[s][nf][3]);                                 \
        bf16x4 pv;                                                            \
        pv[0] = (bf16)p0; pv[1] = (bf16)p1; pv[2] = (bf16)p2; pv[3] = (bf16)p3; \
        *reinterpret_cast<bf16x4*>(&Ps[w][s * 576 + lr * 36 + nn * 16 + g * 4]) = pv; \
      }                                                                       \
    }                                                                         \
    const bf16x8 mfrag = *reinterpret_cast<const bf16x8*>(                    \
        MexpP + (TT) * 64 + (HALF) * 32 + g * 8);                             \
    const bf16* Vb = &Vls[((TT) & 3) * 4096];                                 \
    bf16x8 bv[4];                                                             \
    _Pragma("unroll")                                                         \
    for (int df = 0; df < 4; ++df) {                                          \
      const int r = df * 16 + lr;                                             \
      const int cE = (((HALF) * 64 + lkB) ^ ((r & 7) << 4)) >> 1;             \
      bv[df] = *reinterpret_cast<const bf16x8*>(&Vb[r * 64 + cE]);            \
    }                                                                         \
    bf16x8 ap0, ap1;                                                          \
    {                                                                         \
      const bf16x4 lo0 = *reinterpret_cast<const bf16x4*>(&Ps[w][0 * 576 + lr * 36 + g * 8]); \
      const bf16x4 hi0 = *reinterpret_cast<const bf16x4*>(&Ps[w][0 * 576 + lr * 36 + g * 8 + 4]); \
      const bf16x4 lo1 = *reinterpret_cast<const bf16x4*>(&Ps[w][1 * 576 + lr * 36 + g * 8]); \
      const bf16x4 hi1 = *reinterpret_cast<const bf16x4*>(&Ps[w][1 * 576 + lr * 36 + g * 8 + 4]); \
      _Pragma("unroll")                                                       \
      for (int j = 0; j < 4; ++j) {                                           \
        ap0[j] = lo0[j]; ap0[4 + j] = hi0[j];                                 \
        ap1[j] = lo1[j]; ap1[4 + j] = hi1[j];                                 \
      }                                                                       \
    }                                                                         \
    __builtin_amdgcn_s_setprio(1);                                            \
    acc_l[0] = __builtin_amdgcn_mfma_f32_16x16x32_bf16(ap0, mfrag, acc_l[0], 0, 0, 0); \
    acc_l[1] = __builtin_amdgcn_mfma_f32_16x16x32_bf16(ap1, mfrag, acc_l[1], 0, 0, 0); \
    _Pragma("unroll")                                                         \
    for (int df = 0; df < 4; ++df)                                            \
      acc_o[0][df] = __builtin_amdgcn_mfma_f32_16x16x32_bf16(ap0, bv[df], acc_o[0][df], 0, 0, 0); \
    _Pragma("unroll")                                                         \
    for (int df = 0; df < 4; ++df)                                            \
      acc_o[1][df] = __builtin_amdgcn_mfma_f32_16x16x32_bf16(ap1, bv[df], acc_o[1][df], 0, 0, 0); \
    __builtin_amdgcn_s_setprio(0);                                            \
  } while (0)

// one drain + barrier per PAIR of tiles
#define PAIR_END() do {                                                       \
    asm volatile("s_waitcnt vmcnt(0) lgkmcnt(0)" ::: "memory");               \
    __builtin_amdgcn_s_barrier();                                             \
    __builtin_amdgcn_sched_barrier(0);                                        \
  } while (0)

  f32x4 acc_l[2] = {};
  f32x4 acc_o[2][4] = {};
  f32x4 sA[2][4], sB[2][4];

  constexpr int NT = QL / 64;   // 32 (even)

  // prologue: stage pair {0,1} into bufs 0,1; drain; barrier.
  ATTN_STAGE(0, 0);
  ATTN_STAGE(1, 1);
  asm volatile("s_waitcnt vmcnt(0)" ::: "memory");
  __builtin_amdgcn_s_barrier();

  for (int p = 0; p < NT / 2; ++p) {
    const int T0 = 2 * p, T1 = 2 * p + 1;
    // stage next pair into bufs read LAST iter ((T0+2)&3, (T1+2)&3); clamp tail
    const int s0 = (T0 + 2 < NT) ? T0 + 2 : NT - 2;
    const int s1 = (T1 + 2 < NT) ? T1 + 2 : NT - 1;
    ATTN_STAGE(s0, (T0 + 2) & 3);
    ATTN_STAGE(s1, (T1 + 2) & 3);

    QK_COMPUTE(T0, sA);            // both tiles landed (prev PAIR_END drain)
    QK_COMPUTE(T1, sB);
    SM_PV_HALF(T0, sA, 0);
    SM_PV_HALF(T0, sA, 1);
    SM_PV_HALF(T1, sB, 0);
    SM_PV_HALF(T1, sB, 1);

    PAIR_END();
  }
#undef ATTN_STAGE
#undef QK_COMPUTE
#undef SM_PV_HALF
#undef PAIR_END

  // epilogue: acc_l[s][i] = l for q-row w*32 + s*16 + g*4 + i -> divide
#pragma unroll
  for (int s = 0; s < 2; ++s) {
#pragma unroll
    for (int i = 0; i < 4; ++i) {
      const float inv = 1.0f / acc_l[s][i];
      const size_t r = rowbase + qt * 128 + w * 32 + s * 16 + g * 4 + i;
#pragma unroll
      for (int df = 0; df < 4; ++df)
        ctx[r * DIMC + h * HD + df * 16 + lr] = (bf16)(acc_o[s][df][i] * inv);
    }
  }
}

// ---------------- launch ----------------
extern "C" void kernel_launch(void* const* d_in, const int* in_sizes, int n_in,
                              void* d_out, int out_size, void* d_ws, size_t ws_size,
                              hipStream_t stream) {
  const float* x    = (const float*)d_in[0];
  const float* mask = (const float*)d_in[1];
  const float* qw = (const float*)d_in[2]; const float* qb = (const float*)d_in[3];
  const float* kw = (const float*)d_in[4]; const float* kb = (const float*)d_in[5];
  const float* vw = (const float*)d_in[6]; const float* vb = (const float*)d_in[7];
  const float* ow = (const float*)d_in[8]; const float* ob = (const float*)d_in[9];
  float* out = (float*)d_out;

  // workspace layout (bf16 elements); ctx uses the (unwritten) V slot
  bf16* Xb  = (bf16*)d_ws;
  bf16* Wqb = Xb  + (size_t)MTOT * DIMC;
  bf16* Wkb = Wqb + (size_t)DIMC * DIMC;
  bf16* Wvb = Wkb + (size_t)DIMC * DIMC;
  bf16* Wob = Wvb + (size_t)DIMC * DIMC;
  bf16* Qb  = Wob + (size_t)DIMC * DIMC;
  bf16* Kb  = Qb  + (size_t)MTOT * DIMC;
  bf16* Cb  = Kb  + (size_t)MTOT * DIMC;   // ctx (V slot; V never materialized)
  bf16* Vt  = Cb  + (size_t)MTOT * DIMC;
  bf16* Mex = Vt  + (size_t)MTOT * DIMC;   // 4096 bf16

  // merged conversion + Mexp: 8192 blocks cover X/W, 4 extra cover mask
  prep_cvt<<<8196, 256, 0, stream>>>(x, qw, kw, vw, ow, mask,
                                     Xb, Wqb, Wkb, Wvb, Wob, Mex);

  // fused QKV projections: Q=(X Wq^T + bq)*0.125*log2e, K, V->Vt (scaled, transposed)
  gemm_bt<<<dim3(32, 8, 3), 128, 0, stream>>>(
      Xb, Wqb, Wkb, Wvb, qb, kb, vb, Qb, Kb, Vt, Mex, 0.125f * LOG2E);

  attn_fwd<<<512, 256, 0, stream>>>(Qb, Kb, Vt, Mex, Cb);

  // output projection (fp32 out), 128x64 tiles -> 512 blocks
  gemm_o<<<dim3(32, 16), 256, 0, stream>>>(Cb, Wob, ob, out);
}